// Round 1
// baseline (570.816 us; speedup 1.0000x reference)
//
#include <hip/hip_runtime.h>
#include <hip/hip_bf16.h>

// Problem constants
#define B_ 4
#define S_ 2048
#define DIN_ 256
#define DM_ 512
#define H_ 8
#define DH_ 64
#define M_ (B_*S_)          // 8192 rows

typedef short bf16x8 __attribute__((ext_vector_type(8)));
typedef float f32x4 __attribute__((ext_vector_type(4)));

#define MFMA16(a,b,c) __builtin_amdgcn_mfma_f32_16x16x32_bf16((a),(b),(c),0,0,0)

__device__ __forceinline__ unsigned short f2bf(float f) {
  union { float f; unsigned u; } v; v.f = f;
  unsigned r = v.u + 0x7fffu + ((v.u >> 16) & 1u);
  return (unsigned short)(r >> 16);
}

__device__ __forceinline__ f32x4 f32x4_zero() {
  f32x4 v = {0.f, 0.f, 0.f, 0.f};
  return v;
}

// ---------------- fp32 -> bf16 cast (vectorized) ----------------
__global__ void cast_bf16_kernel(const float* __restrict__ in,
                                 unsigned short* __restrict__ out, int n4) {
  int i = blockIdx.x * blockDim.x + threadIdx.x;
  if (i < n4) {
    float4 v = ((const float4*)in)[i];
    ushort4 o;
    o.x = f2bf(v.x); o.y = f2bf(v.y); o.z = f2bf(v.z); o.w = f2bf(v.w);
    ((ushort4*)out)[i] = o;
  }
}

// ---------------- weight prep: W[K][N] fp32 -> Wt[N][K] bf16 ----------------
struct WtDesc {
  const float* src[10];
  unsigned short* dst[10];
  int ks[10];   // log2 of K (inner dim of Wt)
};

__global__ void prep_w_kernel(WtDesc d) {
  int m = blockIdx.y;
  int ks = d.ks[m];
  int K = 1 << ks;
  int N = 131072 >> ks;
  int i = blockIdx.x * 256 + threadIdx.x;     // exactly N*K = 131072 threads
  int n = i >> ks, k = i & (K - 1);
  d.dst[m][i] = f2bf(d.src[m][(size_t)k * N + n]);
}

// ---------------- GEMM: out[M][512] = bf16(A[M][K] @ W[K][512] + bias), opt ReLU ----
// Block 256 (4 waves), block tile 64 rows x 128 cols. B-fragments straight from
// L2-resident Wt (contiguous 16B per lane).
template<int K, bool RELU>
__global__ __launch_bounds__(256) void gemm_bias_kernel(
    const unsigned short* __restrict__ A,    // [M][K] bf16
    const unsigned short* __restrict__ Wt,   // [512][K] bf16
    const float* __restrict__ bias,          // [512]
    unsigned short* __restrict__ out) {      // [M][512] bf16
  int w = threadIdx.x >> 6, l = threadIdx.x & 63;
  int lr = l & 15, lg = l >> 4;
  int r0 = blockIdx.x * 64 + w * 16;
  int c0 = blockIdx.y * 128;
  f32x4 acc[8];
#pragma unroll
  for (int t = 0; t < 8; ++t) acc[t] = f32x4_zero();
  const unsigned short* arow = A + (size_t)(r0 + lr) * K + lg * 8;
  for (int kk = 0; kk < K / 32; ++kk) {
    bf16x8 a = *(const bf16x8*)(arow + kk * 32);
#pragma unroll
    for (int t = 0; t < 8; ++t) {
      bf16x8 b = *(const bf16x8*)(Wt + (size_t)(c0 + t * 16 + lr) * K + kk * 32 + lg * 8);
      acc[t] = MFMA16(a, b, acc[t]);
    }
  }
#pragma unroll
  for (int t = 0; t < 8; ++t) {
    int c = c0 + t * 16 + lr;
    float bv = bias[c];
#pragma unroll
    for (int r = 0; r < 4; ++r) {
      int row = r0 + lg * 4 + r;
      float v = acc[t][r] + bv;
      if (RELU) v = fmaxf(v, 0.f);
      out[(size_t)row * DM_ + c] = f2bf(v);
    }
  }
}

// ---------------- GEMM + bias + residual + LayerNorm epilogue ----------------
// A[M][512] @ W[512][256] + bias + res, then:
//   NLN==2:  t1 = LN(y; gA,bA); z = res + t1; out = LN(z; gB,bB) -> outF fp32 + outB bf16
//   NLN==1:  out = LN(y; gA,bA) -> outF fp32 only
// One wave per block, 16 rows x 256 cols per wave (full row for in-register LN).
__device__ __forceinline__ void ln_stats16(const f32x4* acc, float* mu, float* rs) {
#pragma unroll
  for (int r = 0; r < 4; ++r) {
    float s1 = 0.f, s2 = 0.f;
#pragma unroll
    for (int t = 0; t < 16; ++t) { float v = acc[t][r]; s1 += v; s2 += v * v; }
#pragma unroll
    for (int off = 1; off < 16; off <<= 1) {
      s1 += __shfl_xor(s1, off);
      s2 += __shfl_xor(s2, off);
    }
    float m = s1 * (1.f / 256.f);
    float var = s2 * (1.f / 256.f) - m * m;
    mu[r] = m;
    rs[r] = rsqrtf(var + 1e-6f);
  }
}

template<int NLN>
__global__ __launch_bounds__(64) void gemm_ln_kernel(
    const unsigned short* __restrict__ A,    // [M][512] bf16
    const unsigned short* __restrict__ Wt,   // [256][512] bf16
    const float* __restrict__ bias,          // [256]
    const float* __restrict__ res,           // [M][256] fp32
    const float* __restrict__ gA, const float* __restrict__ bA,
    const float* __restrict__ gB, const float* __restrict__ bB,
    float* __restrict__ outF,                // [M][256] fp32
    unsigned short* __restrict__ outB) {     // [M][256] bf16 (NLN==2 only)
  int l = threadIdx.x;
  int lr = l & 15, lg = l >> 4;
  int r0 = blockIdx.x * 16;
  f32x4 acc[16];
#pragma unroll
  for (int t = 0; t < 16; ++t) acc[t] = f32x4_zero();
  const unsigned short* arow = A + (size_t)(r0 + lr) * 512 + lg * 8;
  for (int kk = 0; kk < 16; ++kk) {
    bf16x8 a = *(const bf16x8*)(arow + kk * 32);
#pragma unroll
    for (int t = 0; t < 16; ++t) {
      bf16x8 b = *(const bf16x8*)(Wt + (size_t)(t * 16 + lr) * 512 + kk * 32 + lg * 8);
      acc[t] = MFMA16(a, b, acc[t]);
    }
  }
  // y = acc + bias + res
#pragma unroll
  for (int t = 0; t < 16; ++t) {
    int c = t * 16 + lr;
    float bv = bias[c];
#pragma unroll
    for (int r = 0; r < 4; ++r) {
      int row = r0 + lg * 4 + r;
      acc[t][r] += bv + res[(size_t)row * 256 + c];
    }
  }
  float mu[4], rs[4];
  ln_stats16(acc, mu, rs);
  if constexpr (NLN == 2) {
#pragma unroll
    for (int t = 0; t < 16; ++t) {
      int c = t * 16 + lr;
      float g = gA[c], bb = bA[c];
#pragma unroll
      for (int r = 0; r < 4; ++r) {
        int row = r0 + lg * 4 + r;
        float t1 = (acc[t][r] - mu[r]) * rs[r] * g + bb;
        acc[t][r] = res[(size_t)row * 256 + c] + t1;   // second residual
      }
    }
    float mu2[4], rs2[4];
    ln_stats16(acc, mu2, rs2);
#pragma unroll
    for (int t = 0; t < 16; ++t) {
      int c = t * 16 + lr;
      float g = gB[c], bb = bB[c];
#pragma unroll
      for (int r = 0; r < 4; ++r) {
        int row = r0 + lg * 4 + r;
        float o = (acc[t][r] - mu2[r]) * rs2[r] * g + bb;
        outF[(size_t)row * 256 + c] = o;
        outB[(size_t)row * 256 + c] = f2bf(o);
      }
    }
  } else {
#pragma unroll
    for (int t = 0; t < 16; ++t) {
      int c = t * 16 + lr;
      float g = gA[c], bb = bA[c];
#pragma unroll
      for (int r = 0; r < 4; ++r) {
        int row = r0 + lg * 4 + r;
        float o = (acc[t][r] - mu[r]) * rs[r] * g + bb;
        outF[(size_t)row * 256 + c] = o;
      }
    }
  }
}

// ---------------- Flash attention ----------------
// grid (S/64, H, B), block 256 = 4 waves, wave owns 16 q-rows.
// Q/K/V/O are [B*S][DM] bf16, head h at col offset h*64.
// MASKED: key-padding mask (scores <- NEG where mask==0), NEG = -2^32+1.
#define NEGF (-4294967295.0f)

template<bool MASKED>
__global__ __launch_bounds__(256) void flash_kernel(
    const unsigned short* __restrict__ Q,
    const unsigned short* __restrict__ Kg,
    const unsigned short* __restrict__ Vg,
    const int* __restrict__ mask,            // [B][S] or null
    unsigned short* __restrict__ O) {
  __shared__ __align__(16) unsigned short Ks[64][72];   // K tile, padded stride
  __shared__ __align__(16) unsigned short Vt[64][72];   // V^T tile
  __shared__ __align__(16) unsigned short Pb[4][16][72];// per-wave P (bf16)
  int tid = threadIdx.x;
  int w = tid >> 6, l = tid & 63, lr = l & 15, lg = l >> 4;
  int b = blockIdx.z, h = blockIdx.y;
  size_t bS = (size_t)b * S_;
  int q0 = blockIdx.x * 64 + w * 16;

  const unsigned short* qp = Q + (bS + q0 + lr) * DM_ + h * DH_ + lg * 8;
  bf16x8 qf0 = *(const bf16x8*)qp;
  bf16x8 qf1 = *(const bf16x8*)(qp + 32);

  f32x4 oacc[4];
#pragma unroll
  for (int t = 0; t < 4; ++t) oacc[t] = f32x4_zero();
  float mrun[4], lsum[4];
#pragma unroll
  for (int r = 0; r < 4; ++r) { mrun[r] = -INFINITY; lsum[r] = 0.f; }

  for (int kv0 = 0; kv0 < S_; kv0 += 64) {
    __syncthreads();   // previous iteration's LDS reads done
#pragma unroll
    for (int it = 0; it < 2; ++it) {
      int v = tid + it * 256;
      int k = v >> 3, d8 = (v & 7) * 8;
      bf16x8 kv = *(const bf16x8*)(Kg + (bS + kv0 + k) * DM_ + h * DH_ + d8);
      *(bf16x8*)&Ks[k][d8] = kv;
      bf16x8 vv = *(const bf16x8*)(Vg + (bS + kv0 + k) * DM_ + h * DH_ + d8);
#pragma unroll
      for (int j = 0; j < 8; ++j) Vt[d8 + j][k] = (unsigned short)vv[j];
    }
    __syncthreads();

    // scores: 4 subtiles of 16 keys
    f32x4 sc[4];
#pragma unroll
    for (int t = 0; t < 4; ++t) {
      f32x4 s = f32x4_zero();
      bf16x8 k0 = *(const bf16x8*)&Ks[t * 16 + lr][lg * 8];
      bf16x8 k1 = *(const bf16x8*)&Ks[t * 16 + lr][32 + lg * 8];
      s = MFMA16(qf0, k0, s);
      s = MFMA16(qf1, k1, s);
      sc[t] = s;
    }
    bool valid[4];
    if (MASKED) {
#pragma unroll
      for (int t = 0; t < 4; ++t)
        valid[t] = mask[bS + kv0 + t * 16 + lr] != 0;
    }
#pragma unroll
    for (int t = 0; t < 4; ++t) {
#pragma unroll
      for (int r = 0; r < 4; ++r) {
        float v = sc[t][r] * 0.125f;       // 1/sqrt(64)
        if (MASKED && !valid[t]) v = NEGF;
        sc[t][r] = v;
      }
    }
    // online softmax (row = lg*4+r; cols spread over 16 lanes x 4 tiles)
    float mnew[4], fac[4];
#pragma unroll
    for (int r = 0; r < 4; ++r) {
      float mx = fmaxf(fmaxf(sc[0][r], sc[1][r]), fmaxf(sc[2][r], sc[3][r]));
#pragma unroll
      for (int off = 1; off < 16; off <<= 1) mx = fmaxf(mx, __shfl_xor(mx, off));
      mnew[r] = fmaxf(mrun[r], mx);
      fac[r] = __expf(mrun[r] - mnew[r]);
      mrun[r] = mnew[r];
    }
#pragma unroll
    for (int t = 0; t < 4; ++t)
#pragma unroll
      for (int r = 0; r < 4; ++r)
        sc[t][r] = __expf(sc[t][r] - mnew[r]);
#pragma unroll
    for (int r = 0; r < 4; ++r) {
      float s = sc[0][r] + sc[1][r] + sc[2][r] + sc[3][r];
#pragma unroll
      for (int off = 1; off < 16; off <<= 1) s += __shfl_xor(s, off);
      lsum[r] = lsum[r] * fac[r] + s;
    }
#pragma unroll
    for (int t = 0; t < 4; ++t) {
      oacc[t][0] *= fac[0]; oacc[t][1] *= fac[1];
      oacc[t][2] *= fac[2]; oacc[t][3] *= fac[3];
    }
    // P -> per-wave LDS (bf16), then PV
#pragma unroll
    for (int t = 0; t < 4; ++t)
#pragma unroll
      for (int r = 0; r < 4; ++r)
        Pb[w][lg * 4 + r][t * 16 + lr] = f2bf(sc[t][r]);
    __asm__ volatile("s_waitcnt lgkmcnt(0)" ::: "memory");
#pragma unroll
    for (int t = 0; t < 4; ++t) {
#pragma unroll
      for (int kc = 0; kc < 2; ++kc) {
        bf16x8 pa = *(const bf16x8*)&Pb[w][lr][kc * 32 + lg * 8];
        bf16x8 vb = *(const bf16x8*)&Vt[t * 16 + lr][kc * 32 + lg * 8];
        oacc[t] = MFMA16(pa, vb, oacc[t]);
      }
    }
  }
#pragma unroll
  for (int t = 0; t < 4; ++t) {
#pragma unroll
    for (int r = 0; r < 4; ++r) {
      int row = q0 + lg * 4 + r;
      float o = oacc[t][r] / lsum[r];
      O[(bS + row) * DM_ + h * DH_ + t * 16 + lr] = f2bf(o);
    }
  }
}

// ---------------- host ----------------
extern "C" void kernel_launch(void* const* d_in, const int* in_sizes, int n_in,
                              void* d_out, int out_size, void* d_ws, size_t ws_size,
                              hipStream_t stream) {
  const float* x     = (const float*)d_in[0];
  const float* eo    = (const float*)d_in[1];
  const int*   tmask = (const int*)d_in[2];
  // d_in[3] = src_mask, unused (masked=False in reference cross-attn)
  const float* m1_wq = (const float*)d_in[4];  const float* m1_bq = (const float*)d_in[5];
  const float* m1_wk = (const float*)d_in[6];  const float* m1_bk = (const float*)d_in[7];
  const float* m1_wv = (const float*)d_in[8];  const float* m1_bv = (const float*)d_in[9];
  const float* m1_w2 = (const float*)d_in[10]; const float* m1_b2 = (const float*)d_in[11];
  const float* m1_g  = (const float*)d_in[12]; const float* m1_b  = (const float*)d_in[13];
  const float* m2_wq = (const float*)d_in[14]; const float* m2_bq = (const float*)d_in[15];
  const float* m2_wk = (const float*)d_in[16]; const float* m2_bk = (const float*)d_in[17];
  const float* m2_wv = (const float*)d_in[18]; const float* m2_bv = (const float*)d_in[19];
  const float* m2_w2 = (const float*)d_in[20]; const float* m2_b2 = (const float*)d_in[21];
  const float* m2_g  = (const float*)d_in[22]; const float* m2_b  = (const float*)d_in[23];
  const float* ln1_g = (const float*)d_in[24]; const float* ln1_b = (const float*)d_in[25];
  const float* ln2_g = (const float*)d_in[26]; const float* ln2_b = (const float*)d_in[27];
  const float* ln3_g = (const float*)d_in[28]; const float* ln3_b = (const float*)d_in[29];
  const float* f_w1  = (const float*)d_in[30]; const float* f_b1  = (const float*)d_in[31];
  const float* f_w2  = (const float*)d_in[32]; const float* f_b2  = (const float*)d_in[33];

  char* ws = (char*)d_ws;
  size_t off = 0;
  auto alloc = [&](size_t bytes) -> void* {
    void* p = ws + off;
    off += (bytes + 255) & ~(size_t)255;
    return p;
  };
  unsigned short* wt[10];
  for (int i = 0; i < 10; ++i) wt[i] = (unsigned short*)alloc(131072 * 2);
  unsigned short* xb  = (unsigned short*)alloc((size_t)M_ * DIN_ * 2);
  unsigned short* eb  = (unsigned short*)alloc((size_t)M_ * DIN_ * 2);
  unsigned short* Qb  = (unsigned short*)alloc((size_t)M_ * DM_ * 2);
  unsigned short* Kb  = (unsigned short*)alloc((size_t)M_ * DM_ * 2);
  unsigned short* Vb  = (unsigned short*)alloc((size_t)M_ * DM_ * 2);
  unsigned short* AOb = (unsigned short*)alloc((size_t)M_ * DM_ * 2);
  float*          X1  = (float*)alloc((size_t)M_ * DIN_ * 4);
  unsigned short* X1b = (unsigned short*)alloc((size_t)M_ * DIN_ * 2);
  float*          X2  = (float*)alloc((size_t)M_ * DIN_ * 4);
  unsigned short* X2b = (unsigned short*)alloc((size_t)M_ * DIN_ * 2);
  unsigned short* Hb  = Qb;   // reuse: Q buffer is dead by FFN stage

  // casts
  int n4 = M_ * DIN_ / 4;
  cast_bf16_kernel<<<n4 / 256, 256, 0, stream>>>(x, xb, n4);
  cast_bf16_kernel<<<n4 / 256, 256, 0, stream>>>(eo, eb, n4);

  // weight prep (transpose + bf16)
  WtDesc wd;
  const float* srcs[10] = {m1_wq, m1_wk, m1_wv, m1_w2, m2_wq, m2_wk, m2_wv, m2_w2, f_w1, f_w2};
  int kss[10]           = {8,     8,     8,     9,     8,     8,     8,     9,     8,    9};
  for (int i = 0; i < 10; ++i) { wd.src[i] = srcs[i]; wd.dst[i] = wt[i]; wd.ks[i] = kss[i]; }
  prep_w_kernel<<<dim3(512, 10), 256, 0, stream>>>(wd);

  dim3 gg(M_ / 64, 4);
  dim3 fg(S_ / 64, H_, B_);

  // ---- stage A: masked self-attention ----
  gemm_bias_kernel<256, false><<<gg, 256, 0, stream>>>(xb, wt[0], m1_bq, Qb);
  gemm_bias_kernel<256, false><<<gg, 256, 0, stream>>>(xb, wt[1], m1_bk, Kb);
  gemm_bias_kernel<256, false><<<gg, 256, 0, stream>>>(xb, wt[2], m1_bv, Vb);
  flash_kernel<true><<<fg, 256, 0, stream>>>(Qb, Kb, Vb, tmask, AOb);
  gemm_ln_kernel<2><<<M_ / 16, 64, 0, stream>>>(AOb, wt[3], m1_b2, x,
                                                m1_g, m1_b, ln1_g, ln1_b, X1, X1b);
  // ---- stage B: cross-attention (unmasked) ----
  gemm_bias_kernel<256, false><<<gg, 256, 0, stream>>>(X1b, wt[4], m2_bq, Qb);
  gemm_bias_kernel<256, false><<<gg, 256, 0, stream>>>(eb, wt[5], m2_bk, Kb);
  gemm_bias_kernel<256, false><<<gg, 256, 0, stream>>>(eb, wt[6], m2_bv, Vb);
  flash_kernel<false><<<fg, 256, 0, stream>>>(Qb, Kb, Vb, nullptr, AOb);
  gemm_ln_kernel<2><<<M_ / 16, 64, 0, stream>>>(AOb, wt[7], m2_b2, X1,
                                                m2_g, m2_b, ln2_g, ln2_b, X2, X2b);
  // ---- stage C: FFN ----
  gemm_bias_kernel<256, true><<<gg, 256, 0, stream>>>(X2b, wt[8], f_b1, Hb);
  gemm_ln_kernel<1><<<M_ / 16, 64, 0, stream>>>(Hb, wt[9], f_b2, X2,
                                                ln3_g, ln3_b, nullptr, nullptr,
                                                (float*)d_out, nullptr);
}

// Round 2
// 360.655 us; speedup vs baseline: 1.5827x; 1.5827x over previous
//
#include <hip/hip_runtime.h>
#include <hip/hip_bf16.h>

#define B_ 4
#define S_ 2048
#define DIN_ 256
#define DM_ 512
#define H_ 8
#define DH_ 64
#define M_ (B_*S_)

typedef short bf16x8 __attribute__((ext_vector_type(8)));
typedef float f32x4 __attribute__((ext_vector_type(4)));
typedef float f32x16 __attribute__((ext_vector_type(16)));
typedef int v2i __attribute__((ext_vector_type(2)));
typedef unsigned int u32;

#define MFMA16(a,b,c) __builtin_amdgcn_mfma_f32_16x16x32_bf16((a),(b),(c),0,0,0)
#define MFMA32(a,b,c) __builtin_amdgcn_mfma_f32_32x32x16_bf16((a),(b),(c),0,0,0)

__device__ __forceinline__ unsigned short f2bf(float f) {
  union { float f; unsigned u; } v; v.f = f;
  unsigned r = v.u + 0x7fffu + ((v.u >> 16) & 1u);
  return (unsigned short)(r >> 16);
}
__device__ __forceinline__ f32x4 f32x4_zero() { f32x4 v = {0.f,0.f,0.f,0.f}; return v; }
__device__ __forceinline__ f32x16 f32x16_zero() {
  f32x16 v;
#pragma unroll
  for (int i = 0; i < 16; ++i) v[i] = 0.f;
  return v;
}
__device__ __forceinline__ u32 cvtpk_bf16(float lo, float hi) {
  u32 r; asm("v_cvt_pk_bf16_f32 %0, %1, %2" : "=v"(r) : "v"(lo), "v"(hi)); return r;
}
__device__ __forceinline__ void gload_lds16(const void* g, void* l) {
  __builtin_amdgcn_global_load_lds((const __attribute__((address_space(1))) unsigned int*)g,
                                   (__attribute__((address_space(3))) unsigned int*)l,
                                   16, 0, 0);
}

// ---------------- fp32 -> bf16 cast ----------------
__global__ void cast_bf16_kernel(const float* __restrict__ in,
                                 unsigned short* __restrict__ out, int n4) {
  int i = blockIdx.x * blockDim.x + threadIdx.x;
  if (i < n4) {
    float4 v = ((const float4*)in)[i];
    ushort4 o;
    o.x = f2bf(v.x); o.y = f2bf(v.y); o.z = f2bf(v.z); o.w = f2bf(v.w);
    ((ushort4*)out)[i] = o;
  }
}

// ---------------- weight prep: W[K][N] fp32 -> Wt[N][K] bf16 ----------------
struct WtDesc {
  const float* src[10];
  unsigned short* dst[10];
  int ks[10];
};
__global__ void prep_w_kernel(WtDesc d) {
  int m = blockIdx.y;
  int ks = d.ks[m];
  int K = 1 << ks;
  int N = 131072 >> ks;
  int i = blockIdx.x * 256 + threadIdx.x;
  int n = i >> ks, k = i & (K - 1);
  d.dst[m][i] = f2bf(d.src[m][(size_t)k * N + n]);
}

// ---------------- GEMM: out[M][512] = bf16((A[M][256] @ W + bias)*scale) ----
// blockIdx.y selects matrix (y>>2) and 128-col slab (y&3). scale applies to
// matrix 0 only (used to pre-scale Q by 1/sqrt(DH)).
template<int K, bool RELU>
__global__ __launch_bounds__(256) void gemm_bias_kernel(
    const unsigned short* __restrict__ A,
    const unsigned short* __restrict__ W0, const unsigned short* __restrict__ W1,
    const unsigned short* __restrict__ W2,
    const float* __restrict__ b0, const float* __restrict__ b1, const float* __restrict__ b2,
    unsigned short* __restrict__ o0, unsigned short* __restrict__ o1,
    unsigned short* __restrict__ o2, float scale0) {
  int sel = blockIdx.y >> 2;
  const unsigned short* Wt = sel == 0 ? W0 : (sel == 1 ? W1 : W2);
  const float* bias = sel == 0 ? b0 : (sel == 1 ? b1 : b2);
  unsigned short* out = sel == 0 ? o0 : (sel == 1 ? o1 : o2);
  float scale = sel == 0 ? scale0 : 1.f;
  int w = threadIdx.x >> 6, l = threadIdx.x & 63;
  int lr = l & 15, lg = l >> 4;
  int r0 = blockIdx.x * 64 + w * 16;
  int c0 = (blockIdx.y & 3) * 128;
  f32x4 acc[8];
#pragma unroll
  for (int t = 0; t < 8; ++t) acc[t] = f32x4_zero();
  const unsigned short* arow = A + (size_t)(r0 + lr) * K + lg * 8;
  for (int kk = 0; kk < K / 32; ++kk) {
    bf16x8 a = *(const bf16x8*)(arow + kk * 32);
#pragma unroll
    for (int t = 0; t < 8; ++t) {
      bf16x8 b = *(const bf16x8*)(Wt + (size_t)(c0 + t * 16 + lr) * K + kk * 32 + lg * 8);
      acc[t] = MFMA16(a, b, acc[t]);
    }
  }
#pragma unroll
  for (int t = 0; t < 8; ++t) {
    int c = c0 + t * 16 + lr;
    float bv = bias[c];
#pragma unroll
    for (int r = 0; r < 4; ++r) {
      int row = r0 + lg * 4 + r;
      float v = (acc[t][r] + bv) * scale;
      if (RELU) v = fmaxf(v, 0.f);
      out[(size_t)row * DM_ + c] = f2bf(v);
    }
  }
}

// ---------------- GEMM + bias + residual + LayerNorm epilogue ----------------
__device__ __forceinline__ void ln_stats16(const f32x4* acc, float* mu, float* rs) {
#pragma unroll
  for (int r = 0; r < 4; ++r) {
    float s1 = 0.f, s2 = 0.f;
#pragma unroll
    for (int t = 0; t < 16; ++t) { float v = acc[t][r]; s1 += v; s2 += v * v; }
#pragma unroll
    for (int off = 1; off < 16; off <<= 1) {
      s1 += __shfl_xor(s1, off);
      s2 += __shfl_xor(s2, off);
    }
    float m = s1 * (1.f / 256.f);
    float var = s2 * (1.f / 256.f) - m * m;
    mu[r] = m;
    rs[r] = rsqrtf(var + 1e-6f);
  }
}

template<int NLN>
__global__ __launch_bounds__(64) void gemm_ln_kernel(
    const unsigned short* __restrict__ A,
    const unsigned short* __restrict__ Wt,
    const float* __restrict__ bias,
    const float* __restrict__ res,
    const float* __restrict__ gA, const float* __restrict__ bA,
    const float* __restrict__ gB, const float* __restrict__ bB,
    float* __restrict__ outF,
    unsigned short* __restrict__ outB) {
  int l = threadIdx.x;
  int lr = l & 15, lg = l >> 4;
  int r0 = blockIdx.x * 16;
  f32x4 acc[16];
#pragma unroll
  for (int t = 0; t < 16; ++t) acc[t] = f32x4_zero();
  const unsigned short* arow = A + (size_t)(r0 + lr) * 512 + lg * 8;
  for (int kk = 0; kk < 16; ++kk) {
    bf16x8 a = *(const bf16x8*)(arow + kk * 32);
#pragma unroll
    for (int t = 0; t < 16; ++t) {
      bf16x8 b = *(const bf16x8*)(Wt + (size_t)(t * 16 + lr) * 512 + kk * 32 + lg * 8);
      acc[t] = MFMA16(a, b, acc[t]);
    }
  }
#pragma unroll
  for (int t = 0; t < 16; ++t) {
    int c = t * 16 + lr;
    float bv = bias[c];
#pragma unroll
    for (int r = 0; r < 4; ++r) {
      int row = r0 + lg * 4 + r;
      acc[t][r] += bv + res[(size_t)row * 256 + c];
    }
  }
  float mu[4], rs[4];
  ln_stats16(acc, mu, rs);
  if constexpr (NLN == 2) {
#pragma unroll
    for (int t = 0; t < 16; ++t) {
      int c = t * 16 + lr;
      float g = gA[c], bb = bA[c];
#pragma unroll
      for (int r = 0; r < 4; ++r) {
        int row = r0 + lg * 4 + r;
        float t1 = (acc[t][r] - mu[r]) * rs[r] * g + bb;
        acc[t][r] = res[(size_t)row * 256 + c] + t1;
      }
    }
    float mu2[4], rs2[4];
    ln_stats16(acc, mu2, rs2);
#pragma unroll
    for (int t = 0; t < 16; ++t) {
      int c = t * 16 + lr;
      float g = gB[c], bb = bB[c];
#pragma unroll
      for (int r = 0; r < 4; ++r) {
        int row = r0 + lg * 4 + r;
        float o = (acc[t][r] - mu2[r]) * rs2[r] * g + bb;
        outF[(size_t)row * 256 + c] = o;
        outB[(size_t)row * 256 + c] = f2bf(o);
      }
    }
  } else {
#pragma unroll
    for (int t = 0; t < 16; ++t) {
      int c = t * 16 + lr;
      float g = gA[c], bb = bA[c];
#pragma unroll
      for (int r = 0; r < 4; ++r) {
        int row = r0 + lg * 4 + r;
        float o = (acc[t][r] - mu[r]) * rs[r] * g + bb;
        outF[(size_t)row * 256 + c] = o;
      }
    }
  }
}

// ---------------- V transpose: Vb[B*S][512] -> Vt[B][512][2048] ----------------
__global__ __launch_bounds__(256) void trans_kernel(const unsigned short* __restrict__ V,
                                                    unsigned short* __restrict__ Vt) {
  __shared__ __align__(16) unsigned short T[64][72];
  int v = threadIdx.x;
  int b = blockIdx.z;
  int s0 = blockIdx.x * 64, c0 = blockIdx.y * 64;
#pragma unroll
  for (int it = 0; it < 2; ++it) {
    int r = (v >> 3) + it * 32, c8 = (v & 7) * 8;
    *(bf16x8*)&T[r][c8] = *(const bf16x8*)&V[((size_t)b * S_ + s0 + r) * DM_ + c0 + c8];
  }
  __syncthreads();
#pragma unroll
  for (int it = 0; it < 2; ++it) {
    int cr = (v >> 3) + it * 32, s8 = (v & 7) * 8;
    bf16x8 o;
#pragma unroll
    for (int j = 0; j < 8; ++j) o[j] = (short)T[s8 + j][cr];
    *(bf16x8*)&Vt[((size_t)b * DM_ + c0 + cr) * S_ + s0 + s8] = o;
  }
}

// ---------------- Flash attention (32x32 MFMA, swapped QK^T) ----------------
// grid (S/128, H, B), block 256 = 4 waves; wave owns 32 q-rows.
// Q pre-scaled by 1/8. K: [B*S][512] rows. Vt: [B][512][2048] (d-major).
// LDS: 2 dbuf x (K tile [64 k][64 d] + Vt tile [64 d][64 k]), 128B rows,
// XOR-swizzled (slot ^= row&7) for conflict-free b128; staged via
// global_load_lds with inverse-swizzled global source (linear LDS dest).
template<bool MASKED>
__global__ __launch_bounds__(256) void flash_kernel(
    const unsigned short* __restrict__ Q,
    const unsigned short* __restrict__ Kg,
    const unsigned short* __restrict__ Vt,
    const int* __restrict__ mask,
    unsigned short* __restrict__ O) {
  __shared__ __align__(16) unsigned short lds[2][2][64 * 64];
  const int tid = threadIdx.x;
  const int w = tid >> 6, l = tid & 63;
  const int q32 = l & 31, hi = l >> 5;
  const int b = blockIdx.z, h = blockIdx.y;
  const size_t bS = (size_t)b * S_;
  const int q0 = blockIdx.x * 128 + w * 32;

  // Q fragments: lane holds Q[q0+q32][c*16 + hi*8 + j], c=0..3
  bf16x8 qf[4];
  {
    const unsigned short* qp = Q + (bS + q0 + q32) * DM_ + h * DH_;
#pragma unroll
    for (int c = 0; c < 4; ++c) qf[c] = *(const bf16x8*)(qp + c * 16 + hi * 8);
  }

  f32x16 o0 = f32x16_zero(), o1 = f32x16_zero();
  float m = -1e30f, lsum = 0.f;

  // stage tile kv into buffer buf
  auto stage = [&](int buf, int kv0) {
#pragma unroll
    for (int p = 0; p < 2; ++p) {
      int row = p * 32 + w * 8 + (l >> 3);
      int slot = l & 7;
      const unsigned short* src =
          Kg + (bS + kv0 + row) * DM_ + h * DH_ + ((slot ^ (row & 7)) * 8);
      gload_lds16(src, &lds[buf][0][(p * 32 + w * 8) * 64]);
    }
#pragma unroll
    for (int p = 0; p < 2; ++p) {
      int row = p * 32 + w * 8 + (l >> 3);   // d index
      int slot = l & 7;
      const unsigned short* src =
          Vt + ((size_t)b * DM_ + h * DH_ + row) * S_ + kv0 + ((slot ^ (row & 7)) * 8);
      gload_lds16(src, &lds[buf][1][(p * 32 + w * 8) * 64]);
    }
  };

  stage(0, 0);
  __syncthreads();

  const int NT = S_ / 64;
  for (int t = 0; t < NT; ++t) {
    int kv0 = t * 64;
    if (t + 1 < NT) stage((t + 1) & 1, kv0 + 64);

    unsigned long long bits = 0;
    if (MASKED) {
      int mv = mask[bS + kv0 + l];
      bits = __ballot(mv != 0);
    }

    const unsigned short* KB = &lds[t & 1][0][0];
    const unsigned short* VB = &lds[t & 1][1][0];

    // scores: S^T = K . Q^T  (two 32-k subtiles)
    f32x16 sc[2];
#pragma unroll
    for (int kt = 0; kt < 2; ++kt) {
      f32x16 s = f32x16_zero();
#pragma unroll
      for (int c = 0; c < 4; ++c) {
        int row = kt * 32 + q32;
        int slot = (c * 2 + hi) ^ (row & 7);
        bf16x8 kf = *(const bf16x8*)&KB[row * 64 + slot * 8];
        s = MFMA32(kf, qf[c], s);
      }
      sc[kt] = s;
    }

    // tile max for this lane's q (q=q32): in-lane 32 + partner half
    float tm = sc[0][0];
#pragma unroll
    for (int i = 1; i < 16; ++i) tm = fmaxf(tm, sc[0][i]);
#pragma unroll
    for (int i = 0; i < 16; ++i) tm = fmaxf(tm, sc[1][i]);
    tm = fmaxf(tm, __shfl_xor(tm, 32));

    if (__any(tm > m + 8.f)) {        // defer-max (THR=8)
      float mn = fmaxf(m, tm);
      float fac = __expf(m - mn);
      m = mn;
      lsum *= fac;
#pragma unroll
      for (int i = 0; i < 16; ++i) {
        int rq = (i & 3) + 8 * (i >> 2) + 4 * hi;
        float fr = __shfl(fac, rq);
        o0[i] *= fr;
        o1[i] *= fr;
      }
    }

    // p = exp(s - m), mask-zero, rowsum, pack to bf16 pairs
    u32 w8[2][8];
    float rsum = 0.f;
#pragma unroll
    for (int kt = 0; kt < 2; ++kt) {
      u32 bb = 0xFFFFFFFFu;
      if (MASKED) bb = (u32)(bits >> (kt * 32 + 4 * hi));
      float p[16];
#pragma unroll
      for (int i = 0; i < 16; ++i) {
        float pv = __expf(sc[kt][i] - m);
        if (MASKED) {
          const int ci = (i & 3) + 8 * (i >> 2);
          if (!((bb >> ci) & 1)) pv = 0.f;
        }
        p[i] = pv;
        rsum += pv;
      }
#pragma unroll
      for (int j = 0; j < 8; ++j) w8[kt][j] = cvtpk_bf16(p[2 * j], p[2 * j + 1]);
    }
    rsum += __shfl_xor(rsum, 32);
    lsum += rsum;

    // PV: O += P . V   (A-frag = P rows via permlane32_swap, B-frag = V^T tile)
#pragma unroll
    for (int kt = 0; kt < 2; ++kt) {
#pragma unroll
      for (int kc = 0; kc < 2; ++kc) {
        v2i r0 = __builtin_amdgcn_permlane32_swap((int)w8[kt][4 * kc + 0],
                                                  (int)w8[kt][4 * kc + 2], false, false);
        v2i r1 = __builtin_amdgcn_permlane32_swap((int)w8[kt][4 * kc + 1],
                                                  (int)w8[kt][4 * kc + 3], false, false);
        union { u32 u[4]; bf16x8 v; } af;
        af.u[0] = (u32)r0.x; af.u[1] = (u32)r1.x; af.u[2] = (u32)r0.y; af.u[3] = (u32)r1.y;
        {
          int row = 0 * 32 + q32;
          int slot = (kt * 4 + kc * 2 + hi) ^ (row & 7);
          bf16x8 vf = *(const bf16x8*)&VB[row * 64 + slot * 8];
          o0 = MFMA32(af.v, vf, o0);
        }
        {
          int row = 1 * 32 + q32;
          int slot = (kt * 4 + kc * 2 + hi) ^ (row & 7);
          bf16x8 vf = *(const bf16x8*)&VB[row * 64 + slot * 8];
          o1 = MFMA32(af.v, vf, o1);
        }
      }
    }
    __syncthreads();   // stage(t+1) complete; reads of buf[t&1] done
  }

  // epilogue: divide by lsum, store
#pragma unroll
  for (int i = 0; i < 16; ++i) {
    int rq = (i & 3) + 8 * (i >> 2) + 4 * hi;
    float ls = __shfl(lsum, rq);
    float inv = 1.f / ls;
    int row = q0 + rq;
    O[(bS + row) * DM_ + h * DH_ + 0 * 32 + q32] = f2bf(o0[i] * inv);
    O[(bS + row) * DM_ + h * DH_ + 1 * 32 + q32] = f2bf(o1[i] * inv);
  }
}

// ---------------- host ----------------
extern "C" void kernel_launch(void* const* d_in, const int* in_sizes, int n_in,
                              void* d_out, int out_size, void* d_ws, size_t ws_size,
                              hipStream_t stream) {
  const float* x     = (const float*)d_in[0];
  const float* eo    = (const float*)d_in[1];
  const int*   tmask = (const int*)d_in[2];
  const float* m1_wq = (const float*)d_in[4];  const float* m1_bq = (const float*)d_in[5];
  const float* m1_wk = (const float*)d_in[6];  const float* m1_bk = (const float*)d_in[7];
  const float* m1_wv = (const float*)d_in[8];  const float* m1_bv = (const float*)d_in[9];
  const float* m1_w2 = (const float*)d_in[10]; const float* m1_b2 = (const float*)d_in[11];
  const float* m1_g  = (const float*)d_in[12]; const float* m1_b  = (const float*)d_in[13];
  const float* m2_wq = (const float*)d_in[14]; const float* m2_bq = (const float*)d_in[15];
  const float* m2_wk = (const float*)d_in[16]; const float* m2_bk = (const float*)d_in[17];
  const float* m2_wv = (const float*)d_in[18]; const float* m2_bv = (const float*)d_in[19];
  const float* m2_w2 = (const float*)d_in[20]; const float* m2_b2 = (const float*)d_in[21];
  const float* m2_g  = (const float*)d_in[22]; const float* m2_b  = (const float*)d_in[23];
  const float* ln1_g = (const float*)d_in[24]; const float* ln1_b = (const float*)d_in[25];
  const float* ln2_g = (const float*)d_in[26]; const float* ln2_b = (const float*)d_in[27];
  const float* ln3_g = (const float*)d_in[28]; const float* ln3_b = (const float*)d_in[29];
  const float* f_w1  = (const float*)d_in[30]; const float* f_b1  = (const float*)d_in[31];
  const float* f_w2  = (const float*)d_in[32]; const float* f_b2  = (const float*)d_in[33];

  char* ws = (char*)d_ws;
  size_t off = 0;
  auto alloc = [&](size_t bytes) -> void* {
    void* p = ws + off;
    off += (bytes + 255) & ~(size_t)255;
    return p;
  };
  unsigned short* wt[10];
  for (int i = 0; i < 10; ++i) wt[i] = (unsigned short*)alloc(131072 * 2);
  unsigned short* xb  = (unsigned short*)alloc((size_t)M_ * DIN_ * 2);
  unsigned short* eb  = (unsigned short*)alloc((size_t)M_ * DIN_ * 2);
  unsigned short* Qb  = (unsigned short*)alloc((size_t)M_ * DM_ * 2);
  unsigned short* Kb  = (unsigned short*)alloc((size_t)M_ * DM_ * 2);
  unsigned short* Vb  = (unsigned short*)alloc((size_t)M_ * DM_ * 2);
  unsigned short* AOb = (unsigned short*)alloc((size_t)M_ * DM_ * 2);
  float*          X1  = (float*)alloc((size_t)M_ * DIN_ * 4);
  unsigned short* X1b = (unsigned short*)alloc((size_t)M_ * DIN_ * 2);
  float*          X2  = (float*)alloc((size_t)M_ * DIN_ * 4);
  unsigned short* X2b = (unsigned short*)alloc((size_t)M_ * DIN_ * 2);
  unsigned short* Hb  = Qb;                      // dead by FFN stage
  unsigned short* VtA = (unsigned short*)X2;     // [B][512][2048] bf16 = 8MB (X2 free til gLN2)
  unsigned short* VtB = xb;                      // xb+eb contiguous 8MB (dead after cross-KV gemm)

  int n4 = M_ * DIN_ / 4;
  cast_bf16_kernel<<<n4 / 256, 256, 0, stream>>>(x, xb, n4);
  cast_bf16_kernel<<<n4 / 256, 256, 0, stream>>>(eo, eb, n4);

  WtDesc wd;
  const float* srcs[10] = {m1_wq, m1_wk, m1_wv, m1_w2, m2_wq, m2_wk, m2_wv, m2_w2, f_w1, f_w2};
  int kss[10]           = {8,     8,     8,     9,     8,     8,     8,     9,     8,    9};
  for (int i = 0; i < 10; ++i) { wd.src[i] = srcs[i]; wd.dst[i] = wt[i]; wd.ks[i] = kss[i]; }
  prep_w_kernel<<<dim3(512, 10), 256, 0, stream>>>(wd);

  dim3 tg(S_ / 64, DM_ / 64, B_);
  dim3 fg(S_ / 128, H_, B_);
  const float QSCALE = 0.125f;   // 1/sqrt(DH)

  // ---- stage A: masked self-attention ----
  gemm_bias_kernel<256, false><<<dim3(M_ / 64, 12), 256, 0, stream>>>(
      xb, wt[0], wt[1], wt[2], m1_bq, m1_bk, m1_bv, Qb, Kb, Vb, QSCALE);
  trans_kernel<<<tg, 256, 0, stream>>>(Vb, VtA);
  flash_kernel<true><<<fg, 256, 0, stream>>>(Qb, Kb, VtA, tmask, AOb);
  gemm_ln_kernel<2><<<M_ / 16, 64, 0, stream>>>(AOb, wt[3], m1_b2, x,
                                                m1_g, m1_b, ln1_g, ln1_b, X1, X1b);
  // ---- stage B: cross-attention (unmasked) ----
  gemm_bias_kernel<256, false><<<dim3(M_ / 64, 4), 256, 0, stream>>>(
      X1b, wt[4], wt[4], wt[4], m2_bq, m2_bq, m2_bq, Qb, Qb, Qb, QSCALE);
  gemm_bias_kernel<256, false><<<dim3(M_ / 64, 8), 256, 0, stream>>>(
      eb, wt[5], wt[6], wt[6], m2_bk, m2_bv, m2_bv, Kb, Vb, Vb, 1.f);
  trans_kernel<<<tg, 256, 0, stream>>>(Vb, VtB);
  flash_kernel<false><<<fg, 256, 0, stream>>>(Qb, Kb, VtB, nullptr, AOb);
  gemm_ln_kernel<2><<<M_ / 16, 64, 0, stream>>>(AOb, wt[7], m2_b2, X1,
                                                m2_g, m2_b, ln2_g, ln2_b, X2, X2b);
  // ---- stage C: FFN ----
  gemm_bias_kernel<256, true><<<dim3(M_ / 64, 4), 256, 0, stream>>>(
      X2b, wt[8], wt[8], wt[8], f_b1, f_b1, f_b1, Hb, Hb, Hb, 1.f);
  gemm_ln_kernel<1><<<M_ / 16, 64, 0, stream>>>(Hb, wt[9], f_b2, X2,
                                                ln3_g, ln3_b, nullptr, nullptr,
                                                (float*)d_out, nullptr);
}

// Round 4
// 236.793 us; speedup vs baseline: 2.4106x; 1.5231x over previous
//
#include <hip/hip_runtime.h>
#include <hip/hip_bf16.h>

#define B_ 4
#define S_ 2048
#define DIN_ 256
#define DM_ 512
#define H_ 8
#define DH_ 64
#define M_ (B_*S_)

typedef short bf16x8 __attribute__((ext_vector_type(8)));
typedef float f32x4 __attribute__((ext_vector_type(4)));
typedef float f32x16 __attribute__((ext_vector_type(16)));
typedef int v2i __attribute__((ext_vector_type(2)));
typedef unsigned int u32;

#define MFMA16(a,b,c) __builtin_amdgcn_mfma_f32_16x16x32_bf16((a),(b),(c),0,0,0)
#define MFMA32(a,b,c) __builtin_amdgcn_mfma_f32_32x32x16_bf16((a),(b),(c),0,0,0)

__device__ __forceinline__ unsigned short f2bf(float f) {
  union { float f; unsigned u; } v; v.f = f;
  unsigned r = v.u + 0x7fffu + ((v.u >> 16) & 1u);
  return (unsigned short)(r >> 16);
}
__device__ __forceinline__ f32x4 f32x4_zero() { f32x4 v = {0.f,0.f,0.f,0.f}; return v; }
__device__ __forceinline__ f32x16 f32x16_zero() {
  f32x16 v;
#pragma unroll
  for (int i = 0; i < 16; ++i) v[i] = 0.f;
  return v;
}
__device__ __forceinline__ u32 cvtpk_bf16(float lo, float hi) {
  u32 r; asm("v_cvt_pk_bf16_f32 %0, %1, %2" : "=v"(r) : "v"(lo), "v"(hi)); return r;
}
__device__ __forceinline__ void gload_lds16(const void* g, void* l) {
  __builtin_amdgcn_global_load_lds((const __attribute__((address_space(1))) unsigned int*)g,
                                   (__attribute__((address_space(3))) unsigned int*)l,
                                   16, 0, 0);
}

// ---------------- fp32 -> bf16 cast ----------------
__global__ void cast_bf16_kernel(const float* __restrict__ in,
                                 unsigned short* __restrict__ out, int n4) {
  int i = blockIdx.x * blockDim.x + threadIdx.x;
  if (i < n4) {
    float4 v = ((const float4*)in)[i];
    ushort4 o;
    o.x = f2bf(v.x); o.y = f2bf(v.y); o.z = f2bf(v.z); o.w = f2bf(v.w);
    ((ushort4*)out)[i] = o;
  }
}

// ---------------- weight prep: W[K][N] fp32 -> Wt[N][K] bf16 ----------------
struct WtDesc {
  const float* src[10];
  unsigned short* dst[10];
  int ks[10];
};
__global__ void prep_w_kernel(WtDesc d) {
  int m = blockIdx.y;
  int ks = d.ks[m];
  int K = 1 << ks;
  int N = 131072 >> ks;
  int i = blockIdx.x * 256 + threadIdx.x;
  int n = i >> ks, k = i & (K - 1);
  d.dst[m][i] = f2bf(d.src[m][(size_t)k * N + n]);
}

// ---------------- tiled GEMM (m97 structure): 128x128 tile, BK=32 ----------------
// out[sel][M][512] = bf16((A[M][K] @ Wt[sel]^T + bias[sel]) * scale), opt ReLU.
// blockIdx.y: sel = y>>2 chooses matrix, (y&3) chooses 128-col slab.
// 4 waves in 2x2; wave tile 64x64 (4x4 16x16x32 frags). LDS double-buffered,
// staged with global_load_lds width 16 (linear [row][32] tiles, 64B rows).
template<int K, bool RELU>
__global__ __launch_bounds__(256) void gemm_tiled_kernel(
    const unsigned short* __restrict__ A,
    const unsigned short* __restrict__ W0, const unsigned short* __restrict__ W1,
    const unsigned short* __restrict__ W2,
    const float* __restrict__ b0, const float* __restrict__ b1, const float* __restrict__ b2,
    unsigned short* __restrict__ o0, unsigned short* __restrict__ o1,
    unsigned short* __restrict__ o2, float scale0) {
  const int sel = blockIdx.y >> 2;
  const unsigned short* Wt = sel == 0 ? W0 : (sel == 1 ? W1 : W2);
  const float* bias = sel == 0 ? b0 : (sel == 1 ? b1 : b2);
  unsigned short* out = sel == 0 ? o0 : (sel == 1 ? o1 : o2);
  const float scale = sel == 0 ? scale0 : 1.f;

  const int tid = threadIdx.x;
  const int w = tid >> 6, l = tid & 63;
  const int lr = l & 15, lg = l >> 4;
  const int wr = w >> 1, wc = w & 1;
  const int r0 = blockIdx.x * 128;
  const int c0 = (blockIdx.y & 3) * 128;

  __shared__ __align__(16) unsigned short As[2][128 * 32];
  __shared__ __align__(16) unsigned short Bs[2][128 * 32];

  f32x4 acc[4][4];
#pragma unroll
  for (int m = 0; m < 4; ++m)
#pragma unroll
    for (int n = 0; n < 4; ++n) acc[m][n] = f32x4_zero();

  auto stage = [&](int buf, int k0) {
#pragma unroll
    for (int i = 0; i < 2; ++i) {
      int c = w * 128 + i * 64 + l;      // 512 chunks of 16B each for A and B
      int row = c >> 2, sl = c & 3;
      gload_lds16(A + (size_t)(r0 + row) * K + k0 + sl * 8,
                  &As[buf][(w * 128 + i * 64) * 8]);
      gload_lds16(Wt + (size_t)(c0 + row) * K + k0 + sl * 8,
                  &Bs[buf][(w * 128 + i * 64) * 8]);
    }
  };

  stage(0, 0);
  __syncthreads();

  const int NT = K / 32;
  for (int t = 0; t < NT; ++t) {
    if (t + 1 < NT) stage((t + 1) & 1, (t + 1) * 32);
    const unsigned short* AB = &As[t & 1][0];
    const unsigned short* BB = &Bs[t & 1][0];
    bf16x8 af[4], bf[4];
#pragma unroll
    for (int m = 0; m < 4; ++m)
      af[m] = *(const bf16x8*)&AB[(wr * 64 + m * 16 + lr) * 32 + lg * 8];
#pragma unroll
    for (int n = 0; n < 4; ++n)
      bf[n] = *(const bf16x8*)&BB[(wc * 64 + n * 16 + lr) * 32 + lg * 8];
#pragma unroll
    for (int m = 0; m < 4; ++m)
#pragma unroll
      for (int n = 0; n < 4; ++n)
        acc[m][n] = MFMA16(af[m], bf[n], acc[m][n]);
    __syncthreads();
  }

#pragma unroll
  for (int n = 0; n < 4; ++n) {
    int col = c0 + wc * 64 + n * 16 + lr;
    float bv = bias[col];
#pragma unroll
    for (int m = 0; m < 4; ++m) {
#pragma unroll
      for (int r = 0; r < 4; ++r) {
        int row = r0 + wr * 64 + m * 16 + lg * 4 + r;
        float v = (acc[m][n][r] + bv) * scale;
        if (RELU) v = fmaxf(v, 0.f);
        out[(size_t)row * DM_ + col] = f2bf(v);
      }
    }
  }
}

// ---------------- GEMM + bias + residual + LayerNorm epilogue (v2) -------------
// Block = 4 waves, 32 rows; wave (wv=w>>1) row-half, (wh=w&1) col-half of 256.
// A[M][512] @ Wt[256][512] + bias + res; LN stats combined across col halves
// via LDS exchange.  NLN==2: two LNs (outF fp32 + outB bf16); NLN==1: one LN.
template<int NLN>
__global__ __launch_bounds__(256) void gemm_ln_kernel(
    const unsigned short* __restrict__ A,
    const unsigned short* __restrict__ Wt,
    const float* __restrict__ bias,
    const float* __restrict__ res,
    const float* __restrict__ gA, const float* __restrict__ bA,
    const float* __restrict__ gB, const float* __restrict__ bB,
    float* __restrict__ outF,
    unsigned short* __restrict__ outB) {
  const int tid = threadIdx.x;
  const int w = tid >> 6, l = tid & 63;
  const int lr = l & 15, lg = l >> 4;
  const int wh = w & 1, wv = w >> 1;
  const int r0 = blockIdx.x * 32;

  __shared__ __align__(16) unsigned short Bs[2][256 * 32];  // 16KB each = 1024 chunks
  __shared__ __align__(16) unsigned short As[2][32 * 32];   // 2KB each = 128 chunks
  __shared__ float ex[32][2][2];                            // [row][colhalf][s1,s2]

  f32x4 acc[8];
#pragma unroll
  for (int n = 0; n < 8; ++n) acc[n] = f32x4_zero();

  auto stage = [&](int buf, int k0) {
#pragma unroll
    for (int i = 0; i < 4; ++i) {        // FIX: 1024 chunks (256 rows x 4 slots)
      int c = w * 256 + i * 64 + l;
      int row = c >> 2, sl = c & 3;
      gload_lds16(Wt + (size_t)row * 512 + k0 + sl * 8,
                  &Bs[buf][(w * 256 + i * 64) * 8]);
    }
    if (w < 2) {                          // 128 chunks for A
      int c = w * 64 + l;
      int row = c >> 2, sl = c & 3;
      gload_lds16(A + (size_t)(r0 + row) * 512 + k0 + sl * 8,
                  &As[buf][w * 64 * 8]);
    }
  };

  stage(0, 0);
  __syncthreads();

  for (int t = 0; t < 16; ++t) {
    if (t + 1 < 16) stage((t + 1) & 1, (t + 1) * 32);
    const unsigned short* BB = &Bs[t & 1][0];
    const unsigned short* AB = &As[t & 1][0];
    bf16x8 a = *(const bf16x8*)&AB[(wv * 16 + lr) * 32 + lg * 8];
#pragma unroll
    for (int n = 0; n < 8; ++n) {
      bf16x8 b = *(const bf16x8*)&BB[(wh * 128 + n * 16 + lr) * 32 + lg * 8];
      acc[n] = MFMA16(a, b, acc[n]);
    }
    __syncthreads();
  }

  // y = acc + bias + res  (keep res in registers for the second residual)
  f32x4 rv[8];
#pragma unroll
  for (int n = 0; n < 8; ++n) {
    int col = wh * 128 + n * 16 + lr;
    float bv = bias[col];
#pragma unroll
    for (int r = 0; r < 4; ++r) {
      int row = r0 + wv * 16 + lg * 4 + r;
      float rr = res[(size_t)row * 256 + col];
      rv[n][r] = rr;
      acc[n][r] += bv + rr;
    }
  }

  // --- LN stats pass 1 (partials over this wave's 128 cols, combine halves) ---
  float mu[4], rs[4];
  {
    float s1[4], s2[4];
#pragma unroll
    for (int r = 0; r < 4; ++r) {
      float a1 = 0.f, a2 = 0.f;
#pragma unroll
      for (int n = 0; n < 8; ++n) { float v = acc[n][r]; a1 += v; a2 += v * v; }
#pragma unroll
      for (int off = 1; off < 16; off <<= 1) {
        a1 += __shfl_xor(a1, off);
        a2 += __shfl_xor(a2, off);
      }
      s1[r] = a1; s2[r] = a2;
    }
    if (lr == 0) {
#pragma unroll
      for (int r = 0; r < 4; ++r) {
        ex[wv * 16 + lg * 4 + r][wh][0] = s1[r];
        ex[wv * 16 + lg * 4 + r][wh][1] = s2[r];
      }
    }
    __syncthreads();
#pragma unroll
    for (int r = 0; r < 4; ++r) {
      int row = wv * 16 + lg * 4 + r;
      float t1 = ex[row][0][0] + ex[row][1][0];
      float t2 = ex[row][0][1] + ex[row][1][1];
      float m = t1 * (1.f / 256.f);
      float var = t2 * (1.f / 256.f) - m * m;
      mu[r] = m;
      rs[r] = rsqrtf(var + 1e-6f);
    }
  }

  if constexpr (NLN == 2) {
    // z = res + LN1(y)
#pragma unroll
    for (int n = 0; n < 8; ++n) {
      int col = wh * 128 + n * 16 + lr;
      float g = gA[col], bb = bA[col];
#pragma unroll
      for (int r = 0; r < 4; ++r) {
        float t1 = (acc[n][r] - mu[r]) * rs[r] * g + bb;
        acc[n][r] = rv[n][r] + t1;
      }
    }
    // --- LN stats pass 2 ---
    float mu2[4], rs2[4];
    {
      float s1[4], s2[4];
#pragma unroll
      for (int r = 0; r < 4; ++r) {
        float a1 = 0.f, a2 = 0.f;
#pragma unroll
        for (int n = 0; n < 8; ++n) { float v = acc[n][r]; a1 += v; a2 += v * v; }
#pragma unroll
        for (int off = 1; off < 16; off <<= 1) {
          a1 += __shfl_xor(a1, off);
          a2 += __shfl_xor(a2, off);
        }
        s1[r] = a1; s2[r] = a2;
      }
      __syncthreads();    // everyone done reading ex pass 1
      if (lr == 0) {
#pragma unroll
        for (int r = 0; r < 4; ++r) {
          ex[wv * 16 + lg * 4 + r][wh][0] = s1[r];
          ex[wv * 16 + lg * 4 + r][wh][1] = s2[r];
        }
      }
      __syncthreads();
#pragma unroll
      for (int r = 0; r < 4; ++r) {
        int row = wv * 16 + lg * 4 + r;
        float t1 = ex[row][0][0] + ex[row][1][0];
        float t2 = ex[row][0][1] + ex[row][1][1];
        float m = t1 * (1.f / 256.f);
        float var = t2 * (1.f / 256.f) - m * m;
        mu2[r] = m;
        rs2[r] = rsqrtf(var + 1e-6f);
      }
    }
#pragma unroll
    for (int n = 0; n < 8; ++n) {
      int col = wh * 128 + n * 16 + lr;
      float g = gB[col], bb = bB[col];
#pragma unroll
      for (int r = 0; r < 4; ++r) {
        int row = r0 + wv * 16 + lg * 4 + r;
        float o = (acc[n][r] - mu2[r]) * rs2[r] * g + bb;
        outF[(size_t)row * 256 + col] = o;
        outB[(size_t)row * 256 + col] = f2bf(o);
      }
    }
  } else {
#pragma unroll
    for (int n = 0; n < 8; ++n) {
      int col = wh * 128 + n * 16 + lr;
      float g = gA[col], bb = bA[col];
#pragma unroll
      for (int r = 0; r < 4; ++r) {
        int row = r0 + wv * 16 + lg * 4 + r;
        float o = (acc[n][r] - mu[r]) * rs[r] * g + bb;
        outF[(size_t)row * 256 + col] = o;
      }
    }
  }
}

// ---------------- V transpose: Vb[B*S][512] -> Vt[B][512][2048] ----------------
__global__ __launch_bounds__(256) void trans_kernel(const unsigned short* __restrict__ V,
                                                    unsigned short* __restrict__ Vt) {
  __shared__ __align__(16) unsigned short T[64][72];
  int v = threadIdx.x;
  int b = blockIdx.z;
  int s0 = blockIdx.x * 64, c0 = blockIdx.y * 64;
#pragma unroll
  for (int it = 0; it < 2; ++it) {
    int r = (v >> 3) + it * 32, c8 = (v & 7) * 8;
    *(bf16x8*)&T[r][c8] = *(const bf16x8*)&V[((size_t)b * S_ + s0 + r) * DM_ + c0 + c8];
  }
  __syncthreads();
#pragma unroll
  for (int it = 0; it < 2; ++it) {
    int cr = (v >> 3) + it * 32, s8 = (v & 7) * 8;
    bf16x8 o;
#pragma unroll
    for (int j = 0; j < 8; ++j) o[j] = (short)T[s8 + j][cr];
    *(bf16x8*)&Vt[((size_t)b * DM_ + c0 + cr) * S_ + s0 + s8] = o;
  }
}

// ---------------- Flash attention (32x32 MFMA, swapped QK^T) ----------------
#define NEGF (-4294967295.0f)

template<bool MASKED>
__global__ __launch_bounds__(256) void flash_kernel(
    const unsigned short* __restrict__ Q,
    const unsigned short* __restrict__ Kg,
    const unsigned short* __restrict__ Vt,
    const int* __restrict__ mask,
    unsigned short* __restrict__ O) {
  __shared__ __align__(16) unsigned short lds[2][2][64 * 64];
  const int tid = threadIdx.x;
  const int w = tid >> 6, l = tid & 63;
  const int q32 = l & 31, hi = l >> 5;
  const int b = blockIdx.z, h = blockIdx.y;
  const size_t bS = (size_t)b * S_;
  const int q0 = blockIdx.x * 128 + w * 32;

  bf16x8 qf[4];
  {
    const unsigned short* qp = Q + (bS + q0 + q32) * DM_ + h * DH_;
#pragma unroll
    for (int c = 0; c < 4; ++c) qf[c] = *(const bf16x8*)(qp + c * 16 + hi * 8);
  }

  f32x16 o0 = f32x16_zero(), o1 = f32x16_zero();
  float m = -1e30f, lsum = 0.f;

  auto stage = [&](int buf, int kv0) {
#pragma unroll
    for (int p = 0; p < 2; ++p) {
      int row = p * 32 + w * 8 + (l >> 3);
      int slot = l & 7;
      const unsigned short* src =
          Kg + (bS + kv0 + row) * DM_ + h * DH_ + ((slot ^ (row & 7)) * 8);
      gload_lds16(src, &lds[buf][0][(p * 32 + w * 8) * 64]);
    }
#pragma unroll
    for (int p = 0; p < 2; ++p) {
      int row = p * 32 + w * 8 + (l >> 3);
      int slot = l & 7;
      const unsigned short* src =
          Vt + ((size_t)b * DM_ + h * DH_ + row) * S_ + kv0 + ((slot ^ (row & 7)) * 8);
      gload_lds16(src, &lds[buf][1][(p * 32 + w * 8) * 64]);
    }
  };

  stage(0, 0);
  __syncthreads();

  const int NT = S_ / 64;
  for (int t = 0; t < NT; ++t) {
    int kv0 = t * 64;
    if (t + 1 < NT) stage((t + 1) & 1, kv0 + 64);

    unsigned long long bits = 0;
    if (MASKED) {
      int mv = mask[bS + kv0 + l];
      bits = __ballot(mv != 0);
    }

    const unsigned short* KB = &lds[t & 1][0][0];
    const unsigned short* VB = &lds[t & 1][1][0];

    f32x16 sc[2];
#pragma unroll
    for (int kt = 0; kt < 2; ++kt) {
      f32x16 s = f32x16_zero();
#pragma unroll
      for (int c = 0; c < 4; ++c) {
        int row = kt * 32 + q32;
        int slot = (c * 2 + hi) ^ (row & 7);
        bf16x8 kf = *(const bf16x8*)&KB[row * 64 + slot * 8];
        s = MFMA32(kf, qf[c], s);
      }
      sc[kt] = s;
    }

    float tm = sc[0][0];
#pragma unroll
    for (int i = 1; i < 16; ++i) tm = fmaxf(tm, sc[0][i]);
#pragma unroll
    for (int i = 0; i < 16; ++i) tm = fmaxf(tm, sc[1][i]);
    tm = fmaxf(tm, __shfl_xor(tm, 32));

    if (__any(tm > m + 8.f)) {
      float mn = fmaxf(m, tm);
      float fac = __expf(m - mn);
      m = mn;
      lsum *= fac;
#pragma unroll
      for (int i = 0; i < 16; ++i) {
        int rq = (i & 3) + 8 * (i >> 2) + 4 * hi;
        float fr = __shfl(fac, rq);
        o0[i] *= fr;
        o1[i] *= fr;
      }
    }

    u32 w8[2][8];
    float rsum = 0.f;
#pragma unroll
    for (int kt = 0; kt < 2; ++kt) {
      u32 bb = 0xFFFFFFFFu;
      if (MASKED) bb = (u32)(bits >> (kt * 32 + 4 * hi));
      float p[16];
#pragma unroll
      for (int i = 0; i < 16; ++i) {
        float pv = __expf(sc[kt][i] - m);
        if (MASKED) {
          const int ci = (i & 3) + 8 * (i >> 2);
          if (!((bb >> ci) & 1)) pv = 0.f;
        }
        p[i] = pv;
        rsum += pv;
      }
#pragma unroll
      for (int j = 0; j < 8; ++j) w8[kt][j] = cvtpk_bf16(p[2 * j], p[2 * j + 1]);
    }
    rsum += __shfl_xor(rsum, 32);
    lsum += rsum;

#pragma unroll
    for (int kt = 0; kt < 2; ++kt) {
#pragma unroll
      for (int kc = 0; kc < 2; ++kc) {
        v2i r0 = __builtin_amdgcn_permlane32_swap((int)w8[kt][4 * kc + 0],
                                                  (int)w8[kt][4 * kc + 2], false, false);
        v2i r1 = __builtin_amdgcn_permlane32_swap((int)w8[kt][4 * kc + 1],
                                                  (int)w8[kt][4 * kc + 3], false, false);
        union { u32 u[4]; bf16x8 v; } af;
        af.u[0] = (u32)r0.x; af.u[1] = (u32)r1.x; af.u[2] = (u32)r0.y; af.u[3] = (u32)r1.y;
        {
          int row = 0 * 32 + q32;
          int slot = (kt * 4 + kc * 2 + hi) ^ (row & 7);
          bf16x8 vf = *(const bf16x8*)&VB[row * 64 + slot * 8];
          o0 = MFMA32(af.v, vf, o0);
        }
        {
          int row = 1 * 32 + q32;
          int slot = (kt * 4 + kc * 2 + hi) ^ (row & 7);
          bf16x8 vf = *(const bf16x8*)&VB[row * 64 + slot * 8];
          o1 = MFMA32(af.v, vf, o1);
        }
      }
    }
    __syncthreads();
  }

#pragma unroll
  for (int i = 0; i < 16; ++i) {
    int rq = (i & 3) + 8 * (i >> 2) + 4 * hi;
    float ls = __shfl(lsum, rq);
    float inv = 1.f / ls;
    int row = q0 + rq;
    O[(bS + row) * DM_ + h * DH_ + 0 * 32 + q32] = f2bf(o0[i] * inv);
    O[(bS + row) * DM_ + h * DH_ + 1 * 32 + q32] = f2bf(o1[i] * inv);
  }
}

// ---------------- host ----------------
extern "C" void kernel_launch(void* const* d_in, const int* in_sizes, int n_in,
                              void* d_out, int out_size, void* d_ws, size_t ws_size,
                              hipStream_t stream) {
  const float* x     = (const float*)d_in[0];
  const float* eo    = (const float*)d_in[1];
  const int*   tmask = (const int*)d_in[2];
  const float* m1_wq = (const float*)d_in[4];  const float* m1_bq = (const float*)d_in[5];
  const float* m1_wk = (const float*)d_in[6];  const float* m1_bk = (const float*)d_in[7];
  const float* m1_wv = (const float*)d_in[8];  const float* m1_bv = (const float*)d_in[9];
  const float* m1_w2 = (const float*)d_in[10]; const float* m1_b2 = (const float*)d_in[11];
  const float* m1_g  = (const float*)d_in[12]; const float* m1_b  = (const float*)d_in[13];
  const float* m2_wq = (const float*)d_in[14]; const float* m2_bq = (const float*)d_in[15];
  const float* m2_wk = (const float*)d_in[16]; const float* m2_bk = (const float*)d_in[17];
  const float* m2_wv = (const float*)d_in[18]; const float* m2_bv = (const float*)d_in[19];
  const float* m2_w2 = (const float*)d_in[20]; const float* m2_b2 = (const float*)d_in[21];
  const float* m2_g  = (const float*)d_in[22]; const float* m2_b  = (const float*)d_in[23];
  const float* ln1_g = (const float*)d_in[24]; const float* ln1_b = (const float*)d_in[25];
  const float* ln2_g = (const float*)d_in[26]; const float* ln2_b = (const float*)d_in[27];
  const float* ln3_g = (const float*)d_in[28]; const float* ln3_b = (const float*)d_in[29];
  const float* f_w1  = (const float*)d_in[30]; const float* f_b1  = (const float*)d_in[31];
  const float* f_w2  = (const float*)d_in[32]; const float* f_b2  = (const float*)d_in[33];

  char* ws = (char*)d_ws;
  size_t off = 0;
  auto alloc = [&](size_t bytes) -> void* {
    void* p = ws + off;
    off += (bytes + 255) & ~(size_t)255;
    return p;
  };
  unsigned short* wt[10];
  for (int i = 0; i < 10; ++i) wt[i] = (unsigned short*)alloc(131072 * 2);
  unsigned short* xb  = (unsigned short*)alloc((size_t)M_ * DIN_ * 2);
  unsigned short* eb  = (unsigned short*)alloc((size_t)M_ * DIN_ * 2);
  unsigned short* Qb  = (unsigned short*)alloc((size_t)M_ * DM_ * 2);
  unsigned short* Kb  = (unsigned short*)alloc((size_t)M_ * DM_ * 2);
  unsigned short* Vb  = (unsigned short*)alloc((size_t)M_ * DM_ * 2);
  unsigned short* AOb = (unsigned short*)alloc((size_t)M_ * DM_ * 2);
  float*          X1  = (float*)alloc((size_t)M_ * DIN_ * 4);
  unsigned short* X1b = (unsigned short*)alloc((size_t)M_ * DIN_ * 2);
  float*          X2  = (float*)alloc((size_t)M_ * DIN_ * 4);
  unsigned short* X2b = (unsigned short*)alloc((size_t)M_ * DIN_ * 2);
  unsigned short* Hb  = Qb;                      // dead by FFN stage
  unsigned short* VtA = (unsigned short*)X2;     // 8MB (X2 free until gLN2)
  unsigned short* VtB = xb;                      // xb+eb contiguous 8MB (dead after cross-KV gemm)

  int n4 = M_ * DIN_ / 4;
  cast_bf16_kernel<<<n4 / 256, 256, 0, stream>>>(x, xb, n4);
  cast_bf16_kernel<<<n4 / 256, 256, 0, stream>>>(eo, eb, n4);

  WtDesc wd;
  const float* srcs[10] = {m1_wq, m1_wk, m1_wv, m1_w2, m2_wq, m2_wk, m2_wv, m2_w2, f_w1, f_w2};
  int kss[10]           = {8,     8,     8,     9,     8,     8,     8,     9,     8,    9};
  for (int i = 0; i < 10; ++i) { wd.src[i] = srcs[i]; wd.dst[i] = wt[i]; wd.ks[i] = kss[i]; }
  prep_w_kernel<<<dim3(512, 10), 256, 0, stream>>>(wd);

  dim3 tg(S_ / 64, DM_ / 64, B_);
  dim3 fg(S_ / 128, H_, B_);
  const float QSCALE = 0.125f;   // 1/sqrt(DH)

  // ---- stage A: masked self-attention ----
  gemm_tiled_kernel<256, false><<<dim3(M_ / 128, 12), 256, 0, stream>>>(
      xb, wt[0], wt[1], wt[2], m1_bq, m1_bk, m1_bv, Qb, Kb, Vb, QSCALE);
  trans_kernel<<<tg, 256, 0, stream>>>(Vb, VtA);
  flash_kernel<true><<<fg, 256, 0, stream>>>(Qb, Kb, VtA, tmask, AOb);
  gemm_ln_kernel<2><<<M_ / 32, 256, 0, stream>>>(AOb, wt[3], m1_b2, x,
                                                 m1_g, m1_b, ln1_g, ln1_b, X1, X1b);
  // ---- stage B: cross-attention (unmasked) ----
  gemm_tiled_kernel<256, false><<<dim3(M_ / 128, 4), 256, 0, stream>>>(
      X1b, wt[4], wt[4], wt[4], m2_bq, m2_bq, m2_bq, Qb, Qb, Qb, QSCALE);
  gemm_tiled_kernel<256, false><<<dim3(M_ / 128, 8), 256, 0, stream>>>(
      eb, wt[5], wt[6], wt[6], m2_bk, m2_bv, m2_bv, Kb, Vb, Vb, 1.f);
  trans_kernel<<<tg, 256, 0, stream>>>(Vb, VtB);
  flash_kernel<false><<<fg, 256, 0, stream>>>(Qb, Kb, VtB, nullptr, AOb);
  gemm_ln_kernel<2><<<M_ / 32, 256, 0, stream>>>(AOb, wt[7], m2_b2, X1,
                                                 m2_g, m2_b, ln2_g, ln2_b, X2, X2b);
  // ---- stage C: FFN ----
  gemm_tiled_kernel<256, true><<<dim3(M_ / 128, 4), 256, 0, stream>>>(
      X2b, wt[8], wt[8], wt[8], f_b1, f_b1, f_b1, Hb, Hb, Hb, 1.f);
  gemm_ln_kernel<1><<<M_ / 32, 256, 0, stream>>>(Hb, wt[9], f_b2, X2,
                                                 ln3_g, ln3_b, nullptr, nullptr,
                                                 (float*)d_out, nullptr);
}